// Round 6
// baseline (789.928 us; speedup 1.0000x reference)
//
#include <hip/hip_runtime.h>
#include <hip/hip_cooperative_groups.h>

namespace cg = cooperative_groups;

#define IN_DIM 256
#define HID    128
#define LAT    64
#define B0_LOG 8                  // 256 nodes per bucket
#define B0     256
#define CHUNK  8192               // edges per pass-A chunk
#define GRID_C 512                // cooperative grid (2 blocks/CU @ 256 CU)

typedef __attribute__((ext_vector_type(8))) short short8;
typedef __attribute__((ext_vector_type(4))) float floatx4;

static __device__ __forceinline__ ushort f2bf(float f) {
    union { float f; uint u; } v; v.f = f;
    uint u = v.u;
    uint r = (u + 0x7fffu + ((u >> 16) & 1u)) >> 16;
    return (ushort)r;
}
static __device__ __forceinline__ float bf_lo(uint v) { return __uint_as_float(v << 16); }
static __device__ __forceinline__ float bf_hi(uint v) { return __uint_as_float(v & 0xffff0000u); }

// ================================================================ cooperative prep:
// P0 zero deg | P1 deg_count | P2 scan(row_off)+dinv | P2d bucket cursors | P3 binned edge partition
// packed ebuf entry: (src << 8) | dstLocal   [requires N <= 2^17 and dst-range 256]

// block-local: exclusive-scan 512-entry LDS array with 256 threads
static __device__ void scan512(uint* arr, uint* s, uint tid) {
    uint v0 = arr[tid];
    s[tid] = v0; __syncthreads();
    for (int o = 1; o < 256; o <<= 1) {
        uint x = (tid >= (uint)o) ? s[tid - o] : 0; __syncthreads();
        s[tid] += x; __syncthreads();
    }
    uint incl0 = s[tid]; uint tot0 = s[255]; __syncthreads();
    uint v1 = arr[256 + tid];
    s[tid] = v1; __syncthreads();
    for (int o = 1; o < 256; o <<= 1) {
        uint x = (tid >= (uint)o) ? s[tid - o] : 0; __syncthreads();
        s[tid] += x; __syncthreads();
    }
    uint incl1 = s[tid] + tot0; __syncthreads();
    arr[tid] = incl0 - v0;
    arr[256 + tid] = incl1 - v1;
    __syncthreads();
}

__global__ __launch_bounds__(256) void coop_prep(const int* __restrict__ src, const int* __restrict__ dst,
                                                 int* __restrict__ deg, int* __restrict__ row_off,
                                                 float* __restrict__ dinv, int* __restrict__ bcur,
                                                 uint* __restrict__ ebuf, int* __restrict__ partials,
                                                 int N, int E, int ET, int K, int NB, int C) {
    __shared__ uint scnt[512];
    __shared__ uint soffB[512];
    __shared__ uint sgb[512];
    __shared__ uint sent[CHUNK];
    __shared__ ushort sbkt[CHUNK];
    __shared__ uint s256[256];

    cg::grid_group grid = cg::this_grid();
    const uint tid = threadIdx.x;
    const uint bid = blockIdx.x;
    const uint gthreads = GRID_C * 256;

    // ---- P0: zero deg
    for (int i = bid * 256 + tid; i < N; i += gthreads) deg[i] = 0;
    grid.sync();

    // ---- P1: degree count
    for (int e = bid * 256 + tid; e < E; e += gthreads) atomicAdd(&deg[dst[e]], 1);
    grid.sync();

    // ---- P2a: per-tile inclusive scan of (deg+1)
    if ((int)bid < NB) {
        int i = bid * 256 + tid;
        uint v = (i < N) ? (uint)(deg[i] + 1) : 0;
        s256[tid] = v; __syncthreads();
        for (int o = 1; o < 256; o <<= 1) {
            uint x = (tid >= (uint)o) ? s256[tid - o] : 0; __syncthreads();
            s256[tid] += x; __syncthreads();
        }
        if (i < N) row_off[i + 1] = s256[tid];
        if (tid == 255) partials[bid] = s256[255];
    }
    grid.sync();

    // ---- P2b: block 0 scans tile partials (NB <= 512)
    if (bid == 0) {
        scnt[tid]       = (tid < (uint)NB)       ? (uint)partials[tid]       : 0;
        scnt[256 + tid] = (256 + tid < (uint)NB) ? (uint)partials[256 + tid] : 0;
        __syncthreads();
        scan512(scnt, s256, tid);
        if (tid < (uint)NB)       partials[tid]       = scnt[tid];
        if (256 + tid < (uint)NB) partials[256 + tid] = scnt[256 + tid];
    }
    grid.sync();

    // ---- P2c: finalize row_off + dinv
    for (int i = bid * 256 + tid; i < N; i += gthreads) {
        row_off[i + 1] += partials[i >> 8];
        dinv[i] = rsqrtf((float)deg[i] + 1.0f);
        if (i == 0) row_off[0] = 0;
    }
    grid.sync();

    // ---- P2d: bucket cursors = region starts
    for (int b = bid * 256 + tid; b < K; b += gthreads) bcur[b] = row_off[b << B0_LOG];
    grid.sync();

    // ---- P3: binned partition of ET edges into ebuf (coalesced bucket runs)
    if ((int)bid < C) {
        const int base = bid * CHUNK;
        const int nE = min(CHUNK, ET - base);
        for (int t = tid; t < 512; t += 256) scnt[t] = 0;
        __syncthreads();
        uint pk[32]; ushort bk[32];
        #pragma unroll
        for (int j = 0; j < 32; ++j) {
            int li = j * 256 + tid;
            bk[j] = 0xffff;
            if (li < nE) {
                int e = base + li;
                int d, s;
                if (e < E) { d = dst[e]; s = src[e]; } else { d = s = e - E; }
                uint b = (uint)d >> B0_LOG;
                pk[j] = ((uint)s << 8) | (uint)(d & (B0 - 1));
                bk[j] = (ushort)b;
                atomicAdd(&scnt[b], 1);
            }
        }
        __syncthreads();
        // reserve global spans per bucket
        for (int t = tid; t < K; t += 256) {
            uint c = scnt[t];
            sgb[t] = c ? (uint)atomicAdd(&bcur[t], (int)c) : 0u;
        }
        __syncthreads();
        scan512(scnt, s256, tid);                 // scnt := exclusive local offsets
        for (int t = tid; t < 512; t += 256) soffB[t] = scnt[t];
        __syncthreads();
        #pragma unroll
        for (int j = 0; j < 32; ++j) {
            if (bk[j] != 0xffff) {
                uint r = atomicAdd(&soffB[bk[j]], 1u);
                sent[r] = pk[j];
                sbkt[r] = bk[j];
            }
        }
        __syncthreads();
        for (int i = tid; i < nE; i += 256) {     // coalesced runs per bucket
            uint b = sbkt[i];
            ebuf[sgb[b] + ((uint)i - scnt[b])] = sent[i];
        }
    }
}

// ================================================================ pass B: per-bucket node-rank
// assignment -> final CSR {src, norm}; extra blocks convert weights to bf16-transposed.
__global__ __launch_bounds__(256) void passB_kernel(const uint* __restrict__ ebuf,
                                                    const int* __restrict__ row_off,
                                                    const float* __restrict__ dinv,
                                                    int2* __restrict__ csr, int N, int K,
                                                    const float* __restrict__ W1,
                                                    const float* __restrict__ Wmu,
                                                    const float* __restrict__ Wls,
                                                    ushort* __restrict__ W1T,
                                                    ushort* __restrict__ W2T) {
    const int tid = threadIdx.x;
    if ((int)blockIdx.x >= K) {                   // weight-prep blocks
        int idx = (blockIdx.x - K) * 256 + tid;
        if (idx < IN_DIM * HID) {                 // W1: idx = k*128+n
            int n = idx & 127, k = idx >> 7;
            W1T[n * IN_DIM + k] = f2bf(W1[idx]);
        } else {
            int j = idx - IN_DIM * HID;
            if (j < HID * LAT) {                  // Wmu: j = k*64+n
                int n = j & 63, k = j >> 6;
                W2T[n * HID + k] = f2bf(Wmu[j]);
            } else if (j < 2 * HID * LAT) {
                int jj = j - HID * LAT;
                int n = jj & 63, k = jj >> 6;
                W2T[(64 + n) * HID + k] = f2bf(Wls[jj]);
            }
        }
        return;
    }
    __shared__ int   rgoff[B0 + 1];
    __shared__ float ddv[B0];
    __shared__ int   cur[B0];
    const int lo = blockIdx.x << B0_LOG;
    const int nn = min(B0, N - lo);
    for (int t = tid; t <= nn; t += 256) rgoff[t] = row_off[lo + t];
    for (int t = tid; t < nn; t += 256) { ddv[t] = dinv[lo + t]; cur[t] = 0; }
    __syncthreads();
    const int R0 = rgoff[0];
    const int rsize = rgoff[nn] - R0;
    for (int i = tid; i < rsize; i += 256) {
        uint u = ebuf[R0 + i];
        int dL = u & (B0 - 1);
        int s  = u >> 8;
        float nv = dinv[s] * ddv[dL];
        int pos = rgoff[dL] + atomicAdd(&cur[dL], 1);
        csr[pos] = make_int2(s, __float_as_int(nv));
    }
}

// ================================================================ GEMM1 (MFMA bf16): t1[N,128]bf16 = x @ W1
__global__ __launch_bounds__(256) void gemm1_mfma(const float* __restrict__ X,
                                                  const ushort* __restrict__ W1T,
                                                  ushort* __restrict__ O, int N) {
    __shared__ ushort As[64 * 32];
    __shared__ ushort Bs[128 * 32];
    __shared__ ushort Cs[64 * 128];
    const int tid  = threadIdx.x;
    const int wave = tid >> 6, lane = tid & 63;
    const int q = lane >> 4, ln = lane & 15;
    const int row0 = blockIdx.x * 64;
    floatx4 acc[8] = {};

    for (int k0 = 0; k0 < IN_DIM; k0 += 32) {
        #pragma unroll
        for (int t = 0; t < 2; ++t) {
            int j = t * 256 + tid;
            int r = j >> 3, kc = (j & 7) * 4;
            float4 v = make_float4(0.f, 0.f, 0.f, 0.f);
            if (row0 + r < N)
                v = *(const float4*)(X + (size_t)(row0 + r) * IN_DIM + k0 + kc);
            *(ushort4*)(As + r * 32 + kc) =
                make_ushort4(f2bf(v.x), f2bf(v.y), f2bf(v.z), f2bf(v.w));
        }
        #pragma unroll
        for (int t = 0; t < 2; ++t) {
            int c = t * 256 + tid;
            int n = c >> 2, kc = (c & 3) * 8;
            *(int4*)(Bs + n * 32 + kc) = *(const int4*)(W1T + (size_t)n * IN_DIM + k0 + kc);
        }
        __syncthreads();
        short8 a = *(const short8*)(As + (wave * 16 + ln) * 32 + q * 8);
        #pragma unroll
        for (int t = 0; t < 8; ++t) {
            short8 b = *(const short8*)(Bs + (t * 16 + ln) * 32 + q * 8);
            acc[t] = __builtin_amdgcn_mfma_f32_16x16x32_bf16(a, b, acc[t], 0, 0, 0);
        }
        __syncthreads();
    }
    #pragma unroll
    for (int t = 0; t < 8; ++t)
        #pragma unroll
        for (int r = 0; r < 4; ++r)
            Cs[(wave * 16 + q * 4 + r) * 128 + t * 16 + ln] = f2bf(acc[t][r]);
    __syncthreads();
    #pragma unroll
    for (int t = 0; t < 4; ++t) {
        int j = t * 256 + tid;
        int r = j >> 4, c8 = (j & 15) * 8;
        if (row0 + r < N)
            *(int4*)(O + (size_t)(row0 + r) * HID + c8) = *(const int4*)(Cs + r * 128 + c8);
    }
}

// ================================================================ aggregation v3: quarter-wave grouping
__global__ __launch_bounds__(256) void agg_kernel(const ushort* __restrict__ in,
                                                  ushort* __restrict__ out,
                                                  const int* __restrict__ row_off,
                                                  const int2* __restrict__ csr,
                                                  const float* __restrict__ bias,
                                                  int N, int mode) {
    int wid  = (blockIdx.x * 256 + threadIdx.x) >> 6;
    int lane = threadIdx.x & 63;
    if (wid >= N) return;
    int p = row_off[wid], end = row_off[wid + 1];
    const int q    = lane >> 4;
    const int boff = (lane & 15) * 8;
    float a0=0.f,a1=0.f,a2=0.f,a3=0.f,a4=0.f,a5=0.f,a6=0.f,a7=0.f;
    for (; p + 3 < end; p += 4) {
        int2 e = csr[p + q];
        uint4 v = *(const uint4*)(in + (size_t)e.x * HID + boff);
        float n = __int_as_float(e.y);
        a0 += bf_lo(v.x) * n; a1 += bf_hi(v.x) * n;
        a2 += bf_lo(v.y) * n; a3 += bf_hi(v.y) * n;
        a4 += bf_lo(v.z) * n; a5 += bf_hi(v.z) * n;
        a6 += bf_lo(v.w) * n; a7 += bf_hi(v.w) * n;
    }
    int rem = end - p;
    if (q < rem) {
        int2 e = csr[p + q];
        uint4 v = *(const uint4*)(in + (size_t)e.x * HID + boff);
        float n = __int_as_float(e.y);
        a0 += bf_lo(v.x) * n; a1 += bf_hi(v.x) * n;
        a2 += bf_lo(v.y) * n; a3 += bf_hi(v.y) * n;
        a4 += bf_lo(v.z) * n; a5 += bf_hi(v.z) * n;
        a6 += bf_lo(v.w) * n; a7 += bf_hi(v.w) * n;
    }
    a0 += __shfl_xor(a0, 16); a1 += __shfl_xor(a1, 16);
    a2 += __shfl_xor(a2, 16); a3 += __shfl_xor(a3, 16);
    a4 += __shfl_xor(a4, 16); a5 += __shfl_xor(a5, 16);
    a6 += __shfl_xor(a6, 16); a7 += __shfl_xor(a7, 16);
    a0 += __shfl_xor(a0, 32); a1 += __shfl_xor(a1, 32);
    a2 += __shfl_xor(a2, 32); a3 += __shfl_xor(a3, 32);
    a4 += __shfl_xor(a4, 32); a5 += __shfl_xor(a5, 32);
    a6 += __shfl_xor(a6, 32); a7 += __shfl_xor(a7, 32);
    if (q == 0) {
        if (mode) {
            float4 b0 = *(const float4*)(bias + boff);
            float4 b1 = *(const float4*)(bias + boff + 4);
            a0 = fmaxf(a0 + b0.x, 0.f); a1 = fmaxf(a1 + b0.y, 0.f);
            a2 = fmaxf(a2 + b0.z, 0.f); a3 = fmaxf(a3 + b0.w, 0.f);
            a4 = fmaxf(a4 + b1.x, 0.f); a5 = fmaxf(a5 + b1.y, 0.f);
            a6 = fmaxf(a6 + b1.z, 0.f); a7 = fmaxf(a7 + b1.w, 0.f);
        }
        uint4 pk;
        pk.x = (uint)f2bf(a0) | ((uint)f2bf(a1) << 16);
        pk.y = (uint)f2bf(a2) | ((uint)f2bf(a3) << 16);
        pk.z = (uint)f2bf(a4) | ((uint)f2bf(a5) << 16);
        pk.w = (uint)f2bf(a6) | ((uint)f2bf(a7) << 16);
        *(uint4*)(out + (size_t)wid * HID + boff) = pk;
    }
}

// ================================================================ GEMM2 (MFMA bf16): mu/ls = g @ W2T + bias
__global__ __launch_bounds__(256) void gemm2_mfma(const ushort* __restrict__ G,
                                                  const ushort* __restrict__ W2T,
                                                  const float* __restrict__ bmu,
                                                  const float* __restrict__ bls,
                                                  float* __restrict__ mu,
                                                  float* __restrict__ ls, int N) {
    __shared__ ushort As[64 * 32];
    __shared__ ushort Bs[128 * 32];
    __shared__ float  Cs[64 * 128];
    const int tid  = threadIdx.x;
    const int wave = tid >> 6, lane = tid & 63;
    const int q = lane >> 4, ln = lane & 15;
    const int row0 = blockIdx.x * 64;
    floatx4 acc[8] = {};

    for (int k0 = 0; k0 < HID; k0 += 32) {
        {
            int r = tid >> 2, kc = (tid & 3) * 8;
            int4 v = make_int4(0, 0, 0, 0);
            if (row0 + r < N) v = *(const int4*)(G + (size_t)(row0 + r) * HID + k0 + kc);
            *(int4*)(As + r * 32 + kc) = v;
        }
        #pragma unroll
        for (int t = 0; t < 2; ++t) {
            int c = t * 256 + tid;
            int n = c >> 2, kc = (c & 3) * 8;
            *(int4*)(Bs + n * 32 + kc) = *(const int4*)(W2T + (size_t)n * HID + k0 + kc);
        }
        __syncthreads();
        short8 a = *(const short8*)(As + (wave * 16 + ln) * 32 + q * 8);
        #pragma unroll
        for (int t = 0; t < 8; ++t) {
            short8 b = *(const short8*)(Bs + (t * 16 + ln) * 32 + q * 8);
            acc[t] = __builtin_amdgcn_mfma_f32_16x16x32_bf16(a, b, acc[t], 0, 0, 0);
        }
        __syncthreads();
    }
    #pragma unroll
    for (int t = 0; t < 8; ++t)
        #pragma unroll
        for (int r = 0; r < 4; ++r)
            Cs[(wave * 16 + q * 4 + r) * 128 + t * 16 + ln] = acc[t][r];
    __syncthreads();
    #pragma unroll
    for (int t = 0; t < 8; ++t) {
        int j = t * 256 + tid;
        int r = j >> 5, c4 = (j & 31) * 4;
        if (row0 + r < N) {
            float4 v = *(const float4*)(Cs + r * 128 + c4);
            if (c4 < 64) {
                float4 b = *(const float4*)(bmu + c4);
                *(float4*)(mu + (size_t)(row0 + r) * LAT + c4) =
                    make_float4(v.x + b.x, v.y + b.y, v.z + b.z, v.w + b.w);
            } else {
                float4 b = *(const float4*)(bls + (c4 - 64));
                *(float4*)(ls + (size_t)(row0 + r) * LAT + (c4 - 64)) =
                    make_float4(v.x + b.x, v.y + b.y, v.z + b.z, v.w + b.w);
            }
        }
    }
}

// ================================================================ launch
extern "C" void kernel_launch(void* const* d_in, const int* in_sizes, int n_in,
                              void* d_out, int out_size, void* d_ws, size_t ws_size,
                              hipStream_t stream) {
    const float* x    = (const float*)d_in[0];
    const int*   edge = (const int*)d_in[1];
    const float* W1   = (const float*)d_in[2];
    const float* b1   = (const float*)d_in[3];
    const float* Wmu  = (const float*)d_in[4];
    const float* bmu  = (const float*)d_in[5];
    const float* Wls  = (const float*)d_in[6];
    const float* bls  = (const float*)d_in[7];

    const int N  = in_sizes[0] / IN_DIM;
    const int E  = in_sizes[1] / 2;
    const int ET = E + N;
    const int K  = (N + B0 - 1) >> B0_LOG;        // buckets
    const int NB = (N + 255) / 256;               // scan tiles
    const int C  = (ET + CHUNK - 1) / CHUNK;      // pass-A chunks

    const int* srcp = edge;
    const int* dstp = edge + E;

    // workspace layout
    ushort* t1b  = (ushort*)d_ws;                       // [N,128] bf16
    ushort* hb   = t1b + (size_t)N * HID;               // [N,128] bf16
    ushort* gb   = hb + (size_t)N * HID;                // [N,128] bf16
    int2*   csr  = (int2*)(gb + (size_t)N * HID);       // [ET]
    uint*   ebuf = (uint*)(csr + ET);                   // [ET] packed partition
    float*  dinv = (float*)(ebuf + ET);                 // [N]
    int* row_off = (int*)(dinv + N);                    // [N+1]
    int* deg     = row_off + (N + 1);                   // [N]
    int* bcur    = deg + N;                             // [K]
    int* partials= bcur + K;                            // [<=512]
    ushort* W1T  = (ushort*)(partials + 512);           // [128,256] bf16
    ushort* W2T  = W1T + IN_DIM * HID;                  // [128,128] bf16

    float* mu = (float*)d_out;                          // [N,64]
    float* ls = mu + (size_t)N * LAT;                   // [N,64]

    {   // fused preprocessing (cooperative: 6 grid syncs)
        void* args[] = {(void*)&srcp, (void*)&dstp, (void*)&deg, (void*)&row_off,
                        (void*)&dinv, (void*)&bcur, (void*)&ebuf, (void*)&partials,
                        (void*)&N, (void*)&E, (void*)&ET, (void*)&K, (void*)&NB, (void*)&C};
        hipLaunchCooperativeKernel((void*)coop_prep, dim3(GRID_C), dim3(256), args, 0, stream);
    }

    {   // pass B (node-rank CSR) + weight prep folded in
        int WB = (IN_DIM * HID + 2 * HID * LAT + 255) / 256;
        passB_kernel<<<K + WB, 256, 0, stream>>>(ebuf, row_off, dinv, csr, N, K,
                                                 W1, Wmu, Wls, W1T, W2T);
    }

    gemm1_mfma<<<(N + 63) / 64, 256, 0, stream>>>(x, W1T, t1b, N);

    {   // layer-1 aggregation + bias + relu: t1b -> hb
        int blocks = (int)(((long long)N * 64 + 255) / 256);
        agg_kernel<<<blocks, 256, 0, stream>>>(t1b, hb, row_off, csr, b1, N, 1);
    }
    {   // layer-2 aggregation: hb -> gb
        int blocks = (int)(((long long)N * 64 + 255) / 256);
        agg_kernel<<<blocks, 256, 0, stream>>>(hb, gb, row_off, csr, nullptr, N, 0);
    }

    gemm2_mfma<<<(N + 63) / 64, 256, 0, stream>>>(gb, W2T, bmu, bls, mu, ls, N);
}